// Round 2
// baseline (554.318 us; speedup 1.0000x reference)
//
#include <hip/hip_runtime.h>
#include <hip/hip_bf16.h>
#include <math.h>

#define N_NODES 50000
#define N_EDGES 800000
#define F_IN    256
#define HEADS   8
#define C1      32
#define F1      256   // HEADS*C1
#define C2      16
#define NEG     0.2f
#define EPSF    1e-16f

typedef __attribute__((ext_vector_type(8))) short   short8;
typedef __attribute__((ext_vector_type(8))) __bf16  bf16x8;
typedef __attribute__((ext_vector_type(4))) float   floatx4;

__device__ inline short f2bf_rne(float f) {
    unsigned u = __builtin_bit_cast(unsigned, f);
    unsigned r = (u + 0x7FFFu + ((u >> 16) & 1u)) >> 16;
    return (short)r;
}
__device__ inline float bf2f(short s) {
    unsigned u = ((unsigned)(unsigned short)s) << 16;
    return __builtin_bit_cast(float, u);
}

// ---------------- graph build: CSR by dst (self-loops included) -------------

__global__ void k_init_deg(int* __restrict__ deg) {
    int i = blockIdx.x * blockDim.x + threadIdx.x;
    if (i < N_NODES) deg[i] = 1;   // the self-loop
}

__global__ void k_hist(const int* __restrict__ ei, int* __restrict__ deg) {
    int i = blockIdx.x * blockDim.x + threadIdx.x;
    if (i < N_EDGES) atomicAdd(&deg[ei[N_EDGES + i]], 1);
}

// single-block exclusive scan over deg -> offs[N+1], also copies into cursor
__global__ void k_scan(const int* __restrict__ deg, int* __restrict__ offs,
                       int* __restrict__ cursor) {
    __shared__ int wsum[16];
    __shared__ int carry_s;
    int t = threadIdx.x;
    int lane = t & 63;
    int w = t >> 6;
    if (t == 0) carry_s = 0;
    __syncthreads();
    for (int base = 0; base < N_NODES; base += 1024) {
        int idx = base + t;
        int v = (idx < N_NODES) ? deg[idx] : 0;
        int sv = v;
        #pragma unroll
        for (int off = 1; off < 64; off <<= 1) {
            int y = __shfl_up(sv, off, 64);
            if (lane >= off) sv += y;
        }
        __syncthreads();   // protect wsum/carry_s from previous iter readers
        if (lane == 63) wsum[w] = sv;
        __syncthreads();
        if (w == 0) {
            int xx = (lane < 16) ? wsum[lane] : 0;
            #pragma unroll
            for (int off = 1; off < 16; off <<= 1) {
                int y = __shfl_up(xx, off, 64);
                if (lane >= off) xx += y;
            }
            if (lane < 16) wsum[lane] = xx;   // inclusive scan of wave sums
        }
        __syncthreads();
        int carry = carry_s;
        int waveoff = (w == 0) ? 0 : wsum[w - 1];
        int exc = carry + waveoff + sv - v;
        if (idx < N_NODES) { offs[idx] = exc; cursor[idx] = exc; }
        __syncthreads();
        if (t == 1023) carry_s = carry + wsum[15];
    }
    __syncthreads();
    if (t == 0) offs[N_NODES] = carry_s;
}

__global__ void k_scatter(const int* __restrict__ ei, int* __restrict__ cursor,
                          int* __restrict__ ssrc) {
    int i = blockIdx.x * blockDim.x + threadIdx.x;
    const int total = N_EDGES + N_NODES;
    if (i >= total) return;
    int s, d;
    if (i < N_EDGES) { s = ei[i]; d = ei[N_EDGES + i]; }
    else             { s = d = i - N_EDGES; }
    int p = atomicAdd(&cursor[d], 1);
    ssrc[p] = s;
}

// ------------- W1 prep: transpose to [n][k], split into bf16 hi/lo ---------
__global__ void k_prep_w1(const float* __restrict__ W1,
                          short* __restrict__ Wth, short* __restrict__ Wtl) {
    int n = blockIdx.x;     // 256
    int k = threadIdx.x;    // 256
    float v = W1[k * 256 + n];
    short h = f2bf_rne(v);
    short lo = f2bf_rne(v - bf2f(h));
    Wth[n * 256 + k] = h;
    Wtl[n * 256 + k] = lo;
}

// ---------------- layer 1 GEMM via split-bf16 MFMA -------------------------
// h1 = x @ W1. Block = 256 thr = 4 waves; block tile 64 rows x 256 cols.
// Wave w: rows blk*64 + w*16 .. +15. 16 n-tiles of 16 cols, K-chunks of 32.
// A frag: row m = lane&15, k = (lane>>4)*8 + j  (32B contiguous fp32 in x)
// B frag: col n = lane&15, k = (lane>>4)*8 + j  (16B contiguous in Wt[n][k])
// D: col = lane&15, row = (lane>>4)*4 + reg
__global__ __launch_bounds__(256) void k_gemm1(
        const float* __restrict__ x,
        const short* __restrict__ Wth, const short* __restrict__ Wtl,
        float* __restrict__ h1) {
    int t = threadIdx.x;
    int w = t >> 6, l = t & 63;
    int lm = l & 15, q = l >> 4;
    int arow = blockIdx.x * 64 + w * 16 + lm;
    int rclamp = (arow < N_NODES) ? arow : (N_NODES - 1);
    const float* xp = x + (size_t)rclamp * 256 + q * 8;

    floatx4 acc[16];
    #pragma unroll
    for (int nt = 0; nt < 16; ++nt) acc[nt] = (floatx4){0.f, 0.f, 0.f, 0.f};

    // lane-invariant part of B address: Wt[(nt*16+lm)][kc*32 + q*8]
    const size_t bbase = (size_t)lm * 256 + q * 8;

    #pragma unroll 1
    for (int kc = 0; kc < 8; ++kc) {
        float4 xa = *(const float4*)(xp + kc * 32);
        float4 xb = *(const float4*)(xp + kc * 32 + 4);
        float xv[8] = {xa.x, xa.y, xa.z, xa.w, xb.x, xb.y, xb.z, xb.w};
        short8 ah, alo;
        #pragma unroll
        for (int j = 0; j < 8; ++j) {
            short hb = f2bf_rne(xv[j]);
            ah[j] = hb;
            alo[j] = f2bf_rne(xv[j] - bf2f(hb));
        }
        bf16x8 ahv = __builtin_bit_cast(bf16x8, ah);
        bf16x8 alv = __builtin_bit_cast(bf16x8, alo);
        const short* bh0 = Wth + bbase + kc * 32;
        const short* bl0 = Wtl + bbase + kc * 32;
        #pragma unroll
        for (int nt = 0; nt < 16; ++nt) {
            bf16x8 bh = __builtin_bit_cast(bf16x8, *(const short8*)(bh0 + nt * 4096));
            bf16x8 bl = __builtin_bit_cast(bf16x8, *(const short8*)(bl0 + nt * 4096));
            acc[nt] = __builtin_amdgcn_mfma_f32_16x16x32_bf16(ahv, bh, acc[nt], 0, 0, 0);
            acc[nt] = __builtin_amdgcn_mfma_f32_16x16x32_bf16(alv, bh, acc[nt], 0, 0, 0);
            acc[nt] = __builtin_amdgcn_mfma_f32_16x16x32_bf16(ahv, bl, acc[nt], 0, 0, 0);
        }
    }

    int rbase = blockIdx.x * 64 + w * 16 + q * 4;
    if (rbase + 3 < N_NODES) {
        #pragma unroll
        for (int r = 0; r < 4; ++r) {
            size_t ro = (size_t)(rbase + r) * 256 + lm;
            #pragma unroll
            for (int nt = 0; nt < 16; ++nt)
                h1[ro + nt * 16] = acc[nt][r];
        }
    } else {
        #pragma unroll
        for (int r = 0; r < 4; ++r) {
            if (rbase + r < N_NODES) {
                size_t ro = (size_t)(rbase + r) * 256 + lm;
                #pragma unroll
                for (int nt = 0; nt < 16; ++nt)
                    h1[ro + nt * 16] = acc[nt][r];
            }
        }
    }
}

// -------- attention coefficients: als/ald = per-head dot(h1, a) ------------
// one wave per row; lane l covers channels 4l..4l+3 (head = l>>3).
__global__ __launch_bounds__(256) void k_att1(
        const float* __restrict__ h1, const float* __restrict__ as1,
        const float* __restrict__ ad1, float* __restrict__ als,
        float* __restrict__ ald) {
    int t = threadIdx.x;
    int row = blockIdx.x * 4 + (t >> 6);
    int l = t & 63;
    float4 h4 = *(const float4*)(h1 + (size_t)row * 256 + 4 * l);
    float4 a4 = *(const float4*)(as1 + 4 * l);
    float4 d4 = *(const float4*)(ad1 + 4 * l);
    float ps = h4.x * a4.x + h4.y * a4.y + h4.z * a4.z + h4.w * a4.w;
    float pd = h4.x * d4.x + h4.y * d4.y + h4.z * d4.z + h4.w * d4.w;
    #pragma unroll
    for (int m = 1; m < 8; m <<= 1) {
        ps += __shfl_xor(ps, m, 64);
        pd += __shfl_xor(pd, m, 64);
    }
    if ((l & 7) == 0) {
        als[row * HEADS + (l >> 3)] = ps;
        ald[row * HEADS + (l >> 3)] = pd;
    }
}

// ------------- layer 1 aggregation (softmax + weighted sum + ELU) ----------
// one block of 256 threads per dst node. Wave w gathers edges e = w, w+4, ...
// lane l covers channels 4l..4l+3 via float4 (head = l>>3).
__global__ __launch_bounds__(256) void k_agg1(
        const int* __restrict__ offs, const int* __restrict__ ssrc,
        const float* __restrict__ h1, const float* __restrict__ als,
        const float* __restrict__ ald, const float* __restrict__ b1,
        float* __restrict__ hpost) {
    __shared__ int    s_lds[64];
    __shared__ float  w_lds[64 * 8];
    __shared__ float  denom_s[8];
    __shared__ float  aldi[8];
    __shared__ float4 red[3][64];
    int t = threadIdx.x;
    int w = t >> 6, l = t & 63;
    int i = blockIdx.x;
    if (t < 8) { denom_s[t] = 0.0f; aldi[t] = ald[i * HEADS + t]; }
    __syncthreads();
    int beg = offs[i], end = offs[i + 1];
    float4 acc = make_float4(0.f, 0.f, 0.f, 0.f);
    float dsum = 0.0f;           // this thread always touches head t&7
    int hsel = l >> 3;
    for (int c0 = beg; c0 < end; c0 += 64) {
        int nc = min(64, end - c0);
        __syncthreads();                 // prev chunk readers done
        if (t < nc) s_lds[t] = ssrc[c0 + t];
        __syncthreads();
        for (int it = t; it < nc * 8; it += 256) {
            int e = it >> 3, hh = it & 7;   // hh == t&7 always
            int s = s_lds[e];
            float v = als[s * HEADS + hh] + aldi[hh];
            v = (v > 0.0f) ? v : NEG * v;
            float wv = __expf(v);
            w_lds[it] = wv;
            dsum += wv;
        }
        __syncthreads();
        #pragma unroll 2
        for (int e = w; e < nc; e += 4) {
            float wv = w_lds[e * 8 + hsel];
            float4 hv = *(const float4*)(h1 + (size_t)s_lds[e] * F1 + 4 * l);
            acc.x += wv * hv.x; acc.y += wv * hv.y;
            acc.z += wv * hv.z; acc.w += wv * hv.w;
        }
    }
    atomicAdd(&denom_s[t & 7], dsum);
    if (w) red[w - 1][l] = acc;
    __syncthreads();
    if (w == 0) {
        float4 r0 = red[0][l], r1 = red[1][l], r2 = red[2][l];
        acc.x += r0.x + r1.x + r2.x;
        acc.y += r0.y + r1.y + r2.y;
        acc.z += r0.z + r1.z + r2.z;
        acc.w += r0.w + r1.w + r2.w;
        float dn = 1.0f / (denom_s[hsel] + EPSF);
        float4 b4 = *(const float4*)(b1 + 4 * l);
        float vx = acc.x * dn + b4.x;
        float vy = acc.y * dn + b4.y;
        float vz = acc.z * dn + b4.z;
        float vw = acc.w * dn + b4.w;
        vx = (vx > 0.f) ? vx : (__expf(vx) - 1.f);
        vy = (vy > 0.f) ? vy : (__expf(vy) - 1.f);
        vz = (vz > 0.f) ? vz : (__expf(vz) - 1.f);
        vw = (vw > 0.f) ? vw : (__expf(vw) - 1.f);
        *(float4*)(hpost + (size_t)i * F1 + 4 * l) = make_float4(vx, vy, vz, vw);
    }
}

// ---------------- layer 2 GEMM: h2 = hpost @ W2, plus al2 ------------------
// block = 256 threads = 16 rows x 16 cols
__global__ __launch_bounds__(256) void k_gemm2(
        const float* __restrict__ hpost, const float* __restrict__ W2,
        const float* __restrict__ as2, const float* __restrict__ ad2,
        float* __restrict__ h2, float* __restrict__ als2, float* __restrict__ ald2) {
    __shared__ float xs[16 * 257];
    __shared__ float w2s[256 * 16];
    int t = threadIdx.x;
    int row0 = blockIdx.x * 16;
    for (int it = 0; it < 16; ++it) {
        xs[it * 257 + t] = hpost[(size_t)(row0 + it) * F1 + t];
        w2s[it * 256 + t] = W2[it * 256 + t];
    }
    __syncthreads();
    int r = t >> 4, c = t & 15;
    float acc = 0.0f;
    for (int k = 0; k < 256; ++k)
        acc += xs[r * 257 + k] * w2s[k * 16 + c];
    int row = row0 + r;
    h2[row * C2 + c] = acc;
    float vs = acc * as2[c];
    float vd = acc * ad2[c];
    #pragma unroll
    for (int m = 1; m < 16; m <<= 1) {
        vs += __shfl_xor(vs, m, 64);
        vd += __shfl_xor(vd, m, 64);
    }
    if (c == 0) { als2[row] = vs; ald2[row] = vd; }
}

// ---------------- layer 2 aggregation -> out -------------------------------
// one wave (64 threads) per dst node. c = t&15 channel, es = t>>4 edge-slice.
__global__ __launch_bounds__(64) void k_agg2(
        const int* __restrict__ offs, const int* __restrict__ ssrc,
        const float* __restrict__ h2, const float* __restrict__ als2,
        const float* __restrict__ ald2, const float* __restrict__ b2,
        float* __restrict__ out) {
    __shared__ int   s_lds[64];
    __shared__ float w_lds[64];
    int t = threadIdx.x;
    int i = blockIdx.x;
    float adi = ald2[i];
    int beg = offs[i], end = offs[i + 1];
    float acc = 0.0f, dsum = 0.0f;
    int c = t & 15, es = t >> 4;
    for (int c0 = beg; c0 < end; c0 += 64) {
        int nc = min(64, end - c0);
        __syncthreads();
        if (t < nc) {
            int s = ssrc[c0 + t];
            s_lds[t] = s;
            float v = als2[s] + adi;
            v = (v > 0.0f) ? v : NEG * v;
            float wv = __expf(v);
            w_lds[t] = wv;
            dsum += wv;
        }
        __syncthreads();
        for (int e = es; e < nc; e += 4)
            acc += w_lds[e] * h2[s_lds[e] * C2 + c];
    }
    #pragma unroll
    for (int m = 1; m < 64; m <<= 1) dsum += __shfl_xor(dsum, m, 64);
    acc += __shfl_xor(acc, 16, 64);
    acc += __shfl_xor(acc, 32, 64);
    if (t < 16) out[i * C2 + t] = acc / (dsum + EPSF) + b2[t];
}

// ---------------------------------------------------------------------------

extern "C" void kernel_launch(void* const* d_in, const int* in_sizes, int n_in,
                              void* d_out, int out_size, void* d_ws, size_t ws_size,
                              hipStream_t stream) {
    const float* x   = (const float*)d_in[0];
    const int*   ei  = (const int*)d_in[1];
    const float* W1  = (const float*)d_in[2];
    const float* as1 = (const float*)d_in[3];
    const float* ad1 = (const float*)d_in[4];
    const float* b1  = (const float*)d_in[5];
    const float* W2  = (const float*)d_in[6];
    const float* as2 = (const float*)d_in[7];
    const float* ad2 = (const float*)d_in[8];
    const float* b2  = (const float*)d_in[9];
    float* out = (float*)d_out;

    char* ws = (char*)d_ws;
    size_t off = 0;
    auto alloc = [&](size_t bytes) {
        off = (off + 255) & ~(size_t)255;
        void* p = ws + off;
        off += bytes;
        return p;
    };
    float* h1    = (float*)alloc((size_t)N_NODES * F1 * 4);
    float* hpost = (float*)alloc((size_t)N_NODES * F1 * 4);
    float* als   = (float*)alloc((size_t)N_NODES * HEADS * 4);
    float* ald   = (float*)alloc((size_t)N_NODES * HEADS * 4);
    float* h2    = (float*)alloc((size_t)N_NODES * C2 * 4);
    float* als2  = (float*)alloc((size_t)N_NODES * 4);
    float* ald2  = (float*)alloc((size_t)N_NODES * 4);
    int*   deg   = (int*)alloc((size_t)N_NODES * 4);
    int*   offs  = (int*)alloc((size_t)(N_NODES + 1) * 4);
    int*   cursor= (int*)alloc((size_t)N_NODES * 4);
    int*   ssrc  = (int*)alloc((size_t)(N_EDGES + N_NODES) * 4);
    short* Wth   = (short*)alloc((size_t)256 * 256 * 2);
    short* Wtl   = (short*)alloc((size_t)256 * 256 * 2);
    (void)ws_size; (void)in_sizes; (void)n_in; (void)out_size;

    k_init_deg<<<(N_NODES + 255) / 256, 256, 0, stream>>>(deg);
    k_hist<<<(N_EDGES + 255) / 256, 256, 0, stream>>>(ei, deg);
    k_scan<<<1, 1024, 0, stream>>>(deg, offs, cursor);
    k_scatter<<<(N_EDGES + N_NODES + 255) / 256, 256, 0, stream>>>(ei, cursor, ssrc);
    k_prep_w1<<<256, 256, 0, stream>>>(W1, Wth, Wtl);
    k_gemm1<<<(N_NODES + 63) / 64, 256, 0, stream>>>(x, Wth, Wtl, h1);
    k_att1<<<N_NODES / 4, 256, 0, stream>>>(h1, as1, ad1, als, ald);
    k_agg1<<<N_NODES, 256, 0, stream>>>(offs, ssrc, h1, als, ald, b1, hpost);
    k_gemm2<<<N_NODES / 16, 256, 0, stream>>>(hpost, W2, as2, ad2, h2, als2, ald2);
    k_agg2<<<N_NODES, 64, 0, stream>>>(offs, ssrc, h2, als2, ald2, b2, out);
}

// Round 3
// 325.710 us; speedup vs baseline: 1.7019x; 1.7019x over previous
//
#include <hip/hip_runtime.h>
#include <hip/hip_bf16.h>
#include <math.h>

#define N_NODES 50000
#define N_EDGES 800000
#define F_IN    256
#define HEADS   8
#define C1      32
#define F1      256   // HEADS*C1
#define C2      16
#define NEG     0.2f
#define EPSF    1e-16f
#define SCAN_B  196   // ceil(50000/256)

typedef __attribute__((ext_vector_type(8))) _Float16 half8;
typedef __attribute__((ext_vector_type(4))) _Float16 half4_t;
typedef __attribute__((ext_vector_type(4))) float    floatx4;

// ---------------- graph build: CSR by dst (self-loops included) -------------

__global__ void k_init_deg(int* __restrict__ deg) {
    int i = blockIdx.x * blockDim.x + threadIdx.x;
    if (i < N_NODES) deg[i] = 1;   // the self-loop
}

__global__ void k_hist(const int* __restrict__ ei, int* __restrict__ deg) {
    int i = blockIdx.x * blockDim.x + threadIdx.x;
    if (i < N_EDGES) atomicAdd(&deg[ei[N_EDGES + i]], 1);
}

// phase 1: per-block sums
__global__ __launch_bounds__(256) void k_scan1(const int* __restrict__ deg,
                                               int* __restrict__ bsum) {
    __shared__ int ws[4];
    int t = threadIdx.x, l = t & 63, w = t >> 6;
    int idx = blockIdx.x * 256 + t;
    int v = (idx < N_NODES) ? deg[idx] : 0;
    #pragma unroll
    for (int m = 1; m < 64; m <<= 1) v += __shfl_xor(v, m, 64);
    if (l == 0) ws[w] = v;
    __syncthreads();
    if (t == 0) bsum[blockIdx.x] = ws[0] + ws[1] + ws[2] + ws[3];
}

// phase 2: exclusive scan of block sums (1 block)
__global__ __launch_bounds__(256) void k_scan2(const int* __restrict__ bsum,
                                               int* __restrict__ boff) {
    __shared__ int ws[4];
    int t = threadIdx.x, l = t & 63, w = t >> 6;
    int v = (t < SCAN_B) ? bsum[t] : 0;
    int sv = v;
    #pragma unroll
    for (int off = 1; off < 64; off <<= 1) {
        int y = __shfl_up(sv, off, 64);
        if (l >= off) sv += y;
    }
    if (l == 63) ws[w] = sv;
    __syncthreads();
    int add = 0;
    for (int j = 0; j < w; ++j) add += ws[j];
    if (t < SCAN_B) boff[t] = add + sv - v;
}

// phase 3: local exclusive scan + block offset -> offs, cursor
__global__ __launch_bounds__(256) void k_scan3(const int* __restrict__ deg,
                                               const int* __restrict__ boff,
                                               int* __restrict__ offs,
                                               int* __restrict__ cursor) {
    __shared__ int ws[4];
    int t = threadIdx.x, l = t & 63, w = t >> 6;
    int idx = blockIdx.x * 256 + t;
    int v = (idx < N_NODES) ? deg[idx] : 0;
    int sv = v;
    #pragma unroll
    for (int off = 1; off < 64; off <<= 1) {
        int y = __shfl_up(sv, off, 64);
        if (l >= off) sv += y;
    }
    if (l == 63) ws[w] = sv;
    __syncthreads();
    int add = boff[blockIdx.x];
    for (int j = 0; j < w; ++j) add += ws[j];
    int exc = add + sv - v;
    if (idx < N_NODES) { offs[idx] = exc; cursor[idx] = exc; }
    if (idx == N_NODES - 1) offs[N_NODES] = exc + v;
}

__global__ void k_scatter(const int* __restrict__ ei, int* __restrict__ cursor,
                          int* __restrict__ ssrc) {
    int i = blockIdx.x * blockDim.x + threadIdx.x;
    const int total = N_EDGES + N_NODES;
    if (i >= total) return;
    int s, d;
    if (i < N_EDGES) { s = ei[i]; d = ei[N_EDGES + i]; }
    else             { s = d = i - N_EDGES; }
    int p = atomicAdd(&cursor[d], 1);
    ssrc[p] = s;
}

// ------------- weight prep: fp16, GEMM-friendly layouts --------------------
// Wp[kc][n][j] : kc = k>>5 (8 chunks), n = 0..255 col of W1, j = k&31.
// W2t[n][k]    : n = 0..15 col of W2.
__global__ void k_prep(const float* __restrict__ W1, const float* __restrict__ W2,
                       _Float16* __restrict__ Wp, _Float16* __restrict__ W2t) {
    int n = blockIdx.x;     // 0..256
    int k = threadIdx.x;    // 0..255
    if (n < 256) {
        float v = W1[k * 256 + n];
        Wp[(k >> 5) * 8192 + n * 32 + (k & 31)] = (_Float16)v;
    } else {
        for (int n2 = 0; n2 < 16; ++n2)
            W2t[n2 * 256 + k] = (_Float16)W2[k * 16 + n2];
    }
}

// ---------------- layer 1 GEMM via split-fp16 MFMA -------------------------
// h1h = fp16(x @ W1). Block = 256 thr = 4 waves; tile 64 rows x 256 cols.
// A = xh + xl (fp16 split, exact to ~2^-22), B = fp16(W1) -> 2 MFMA/(kc,nt).
// B staged per-kc in LDS (16KB), double-buffered, shared by all 4 waves.
__global__ __launch_bounds__(256) void k_gemm1(
        const float* __restrict__ x, const _Float16* __restrict__ Wp,
        _Float16* __restrict__ h1h) {
    __shared__ _Float16 sW[2][8192];
    int t = threadIdx.x;
    int w = t >> 6, l = t & 63;
    int lm = l & 15, q = l >> 4;
    int row0 = blockIdx.x * 64;
    int arow = row0 + w * 16 + lm;
    int rc = (arow < N_NODES) ? arow : (N_NODES - 1);
    const float* xp = x + (size_t)rc * 256 + q * 8;

    floatx4 acc[16];
    #pragma unroll
    for (int nt = 0; nt < 16; ++nt) acc[nt] = (floatx4){0.f, 0.f, 0.f, 0.f};

    auto stage = [&](int kc, int buf) {
        const char* g = (const char*)Wp + (size_t)kc * 16384;
        char* sp = (char*)&sW[buf][0];
        #pragma unroll
        for (int c = 0; c < 4; ++c)
            *(float4*)(sp + c * 4096 + t * 16) =
                *(const float4*)(g + c * 4096 + t * 16);
    };

    stage(0, 0);
    int buf = 0;
    #pragma unroll 1
    for (int kc = 0; kc < 8; ++kc) {
        __syncthreads();
        if (kc < 7) stage(kc + 1, buf ^ 1);

        float4 xa = *(const float4*)(xp + kc * 32);
        float4 xb = *(const float4*)(xp + kc * 32 + 4);
        float xv[8] = {xa.x, xa.y, xa.z, xa.w, xb.x, xb.y, xb.z, xb.w};
        half8 ah, al;
        #pragma unroll
        for (int j = 0; j < 8; ++j) {
            _Float16 h = (_Float16)xv[j];
            ah[j] = h;
            al[j] = (_Float16)(xv[j] - (float)h);
        }
        const _Float16* sb = &sW[buf][(size_t)lm * 32 + q * 8];
        #pragma unroll
        for (int nt = 0; nt < 16; ++nt) {
            half8 b = *(const half8*)(sb + nt * 512);
            acc[nt] = __builtin_amdgcn_mfma_f32_16x16x32_f16(ah, b, acc[nt], 0, 0, 0);
            acc[nt] = __builtin_amdgcn_mfma_f32_16x16x32_f16(al, b, acc[nt], 0, 0, 0);
        }
        buf ^= 1;
    }

    int rbase = row0 + w * 16 + q * 4;
    #pragma unroll
    for (int r = 0; r < 4; ++r) {
        int row = rbase + r;
        if (row < N_NODES) {
            size_t ro = (size_t)row * 256 + lm;
            #pragma unroll
            for (int nt = 0; nt < 16; ++nt)
                h1h[ro + nt * 16] = (_Float16)acc[nt][r];
        }
    }
}

// -------- attention coefficients: als/ald = per-head dot(h1, a) ------------
__global__ __launch_bounds__(256) void k_att1(
        const _Float16* __restrict__ h1h, const float* __restrict__ as1,
        const float* __restrict__ ad1, float* __restrict__ als,
        float* __restrict__ ald) {
    int t = threadIdx.x;
    int row = blockIdx.x * 4 + (t >> 6);
    int l = t & 63;
    half4_t h4 = *(const half4_t*)(h1h + (size_t)row * 256 + 4 * l);
    float4 a4 = *(const float4*)(as1 + 4 * l);
    float4 d4 = *(const float4*)(ad1 + 4 * l);
    float hx = (float)h4[0], hy = (float)h4[1], hz = (float)h4[2], hw = (float)h4[3];
    float ps = hx * a4.x + hy * a4.y + hz * a4.z + hw * a4.w;
    float pd = hx * d4.x + hy * d4.y + hz * d4.z + hw * d4.w;
    #pragma unroll
    for (int m = 1; m < 8; m <<= 1) {
        ps += __shfl_xor(ps, m, 64);
        pd += __shfl_xor(pd, m, 64);
    }
    if ((l & 7) == 0) {
        als[row * HEADS + (l >> 3)] = ps;
        ald[row * HEADS + (l >> 3)] = pd;
    }
}

// ------------- layer 1 aggregation: one wave per dst node ------------------
// lane l covers channels 4l..4l+3 (head = l>>3). Every lane walks every edge,
// so each lane accumulates its head's denom for free (no reductions at all).
__global__ __launch_bounds__(64) void k_agg1(
        const int* __restrict__ offs, const int* __restrict__ ssrc,
        const _Float16* __restrict__ h1h, const float* __restrict__ als,
        const float* __restrict__ ald, const float* __restrict__ b1,
        _Float16* __restrict__ hposth) {
    __shared__ int   s_lds[64];
    __shared__ float w_lds[64 * 8];
    int l = threadIdx.x;
    int i = blockIdx.x;
    int h = l >> 3;
    float4 ad0 = *(const float4*)(ald + i * 8);
    float4 ad1v = *(const float4*)(ald + i * 8 + 4);
    int beg = offs[i], end = offs[i + 1];
    float ax = 0.f, ay = 0.f, az = 0.f, aw = 0.f, dsum = 0.f;
    for (int c0 = beg; c0 < end; c0 += 64) {
        int nc = min(64, end - c0);
        __syncthreads();
        if (l < nc) {
            int s = ssrc[c0 + l];
            s_lds[l] = s;
            float4 s0 = *(const float4*)(als + s * 8);
            float4 s1 = *(const float4*)(als + s * 8 + 4);
            float e0 = s0.x + ad0.x,  e1 = s0.y + ad0.y;
            float e2 = s0.z + ad0.z,  e3 = s0.w + ad0.w;
            float e4 = s1.x + ad1v.x, e5 = s1.y + ad1v.y;
            float e6 = s1.z + ad1v.z, e7 = s1.w + ad1v.w;
            e0 = (e0 > 0.f) ? e0 : NEG * e0;  e1 = (e1 > 0.f) ? e1 : NEG * e1;
            e2 = (e2 > 0.f) ? e2 : NEG * e2;  e3 = (e3 > 0.f) ? e3 : NEG * e3;
            e4 = (e4 > 0.f) ? e4 : NEG * e4;  e5 = (e5 > 0.f) ? e5 : NEG * e5;
            e6 = (e6 > 0.f) ? e6 : NEG * e6;  e7 = (e7 > 0.f) ? e7 : NEG * e7;
            float4 w0 = make_float4(__expf(e0), __expf(e1), __expf(e2), __expf(e3));
            float4 w1 = make_float4(__expf(e4), __expf(e5), __expf(e6), __expf(e7));
            *(float4*)(w_lds + l * 8)     = w0;
            *(float4*)(w_lds + l * 8 + 4) = w1;
        }
        __syncthreads();
        #pragma unroll 2
        for (int e = 0; e < nc; ++e) {
            float wv = w_lds[e * 8 + h];
            int s = s_lds[e];
            half4_t hv = *(const half4_t*)(h1h + (size_t)s * 256 + 4 * l);
            ax += wv * (float)hv[0];
            ay += wv * (float)hv[1];
            az += wv * (float)hv[2];
            aw += wv * (float)hv[3];
            dsum += wv;
        }
    }
    float dn = 1.0f / (dsum + EPSF);
    float4 b4 = *(const float4*)(b1 + 4 * l);
    float vx = ax * dn + b4.x;
    float vy = ay * dn + b4.y;
    float vz = az * dn + b4.z;
    float vw = aw * dn + b4.w;
    vx = (vx > 0.f) ? vx : (__expf(vx) - 1.f);
    vy = (vy > 0.f) ? vy : (__expf(vy) - 1.f);
    vz = (vz > 0.f) ? vz : (__expf(vz) - 1.f);
    vw = (vw > 0.f) ? vw : (__expf(vw) - 1.f);
    half4_t o;
    o[0] = (_Float16)vx; o[1] = (_Float16)vy;
    o[2] = (_Float16)vz; o[3] = (_Float16)vw;
    *(half4_t*)(hposth + (size_t)i * 256 + 4 * l) = o;
}

// ---------------- layer 2 GEMM via fp16 MFMA + fused att2 ------------------
// h2h = fp16(hpost @ W2), als2/ald2 fused. 4 waves x 16 rows per block.
__global__ __launch_bounds__(256) void k_gemm2(
        const _Float16* __restrict__ hposth, const _Float16* __restrict__ W2t,
        const float* __restrict__ as2, const float* __restrict__ ad2,
        _Float16* __restrict__ h2h, float* __restrict__ als2,
        float* __restrict__ ald2) {
    int t = threadIdx.x;
    int w = t >> 6, l = t & 63;
    int lm = l & 15, q = l >> 4;
    int row0 = blockIdx.x * 64;
    int arow = row0 + w * 16 + lm;
    int rc = (arow < N_NODES) ? arow : (N_NODES - 1);
    const _Float16* ap = hposth + (size_t)rc * 256 + q * 8;
    const _Float16* bp = W2t + (size_t)lm * 256 + q * 8;

    floatx4 acc = (floatx4){0.f, 0.f, 0.f, 0.f};
    #pragma unroll
    for (int kc = 0; kc < 8; ++kc) {
        half8 a = *(const half8*)(ap + kc * 32);
        half8 b = *(const half8*)(bp + kc * 32);
        acc = __builtin_amdgcn_mfma_f32_16x16x32_f16(a, b, acc, 0, 0, 0);
    }

    float a_s = as2[lm], a_d = ad2[lm];
    int rbase = row0 + w * 16 + q * 4;
    #pragma unroll
    for (int r = 0; r < 4; ++r) {
        int row = rbase + r;
        float v = acc[r];
        float vs = v * a_s, vd = v * a_d;
        #pragma unroll
        for (int m = 1; m < 16; m <<= 1) {
            vs += __shfl_xor(vs, m, 64);
            vd += __shfl_xor(vd, m, 64);
        }
        if (row < N_NODES) {
            h2h[row * C2 + lm] = (_Float16)v;
            if (lm == 0) { als2[row] = vs; ald2[row] = vd; }
        }
    }
}

// ---------------- layer 2 aggregation -> out (shuffle-only) ----------------
// 4 nodes per block (one wave each). lane: c = l&15 channel, es = l>>4 slice.
__global__ __launch_bounds__(256) void k_agg2(
        const int* __restrict__ offs, const int* __restrict__ ssrc,
        const _Float16* __restrict__ h2h, const float* __restrict__ als2,
        const float* __restrict__ ald2, const float* __restrict__ b2,
        float* __restrict__ out) {
    int t = threadIdx.x;
    int l = t & 63;
    int i = blockIdx.x * 4 + (t >> 6);
    int c = l & 15, es = l >> 4;
    float adi = ald2[i];
    int beg = offs[i], end = offs[i + 1];
    float acc = 0.f, dsum = 0.f;
    for (int c0 = beg; c0 < end; c0 += 64) {
        int nc = min(64, end - c0);
        int s = 0; float wv = 0.f;
        if (l < nc) {
            s = ssrc[c0 + l];
            float v = als2[s] + adi;
            v = (v > 0.f) ? v : NEG * v;
            wv = __expf(v);
            dsum += wv;
        }
        for (int e0 = 0; e0 < nc; e0 += 4) {     // uniform trip count
            int e = e0 + es;
            int ec = (e < nc) ? e : (nc - 1);
            int se = __shfl(s, ec, 64);
            float we = __shfl(wv, ec, 64);
            if (e < nc) acc += we * (float)h2h[(size_t)se * C2 + c];
        }
    }
    #pragma unroll
    for (int m = 1; m < 64; m <<= 1) dsum += __shfl_xor(dsum, m, 64);
    acc += __shfl_xor(acc, 16, 64);
    acc += __shfl_xor(acc, 32, 64);
    if (l < 16) out[i * C2 + l] = acc / (dsum + EPSF) + b2[l];
}

// ---------------------------------------------------------------------------

extern "C" void kernel_launch(void* const* d_in, const int* in_sizes, int n_in,
                              void* d_out, int out_size, void* d_ws, size_t ws_size,
                              hipStream_t stream) {
    const float* x   = (const float*)d_in[0];
    const int*   ei  = (const int*)d_in[1];
    const float* W1  = (const float*)d_in[2];
    const float* as1 = (const float*)d_in[3];
    const float* ad1 = (const float*)d_in[4];
    const float* b1  = (const float*)d_in[5];
    const float* W2  = (const float*)d_in[6];
    const float* as2 = (const float*)d_in[7];
    const float* ad2 = (const float*)d_in[8];
    const float* b2  = (const float*)d_in[9];
    float* out = (float*)d_out;

    char* ws = (char*)d_ws;
    size_t off = 0;
    auto alloc = [&](size_t bytes) {
        off = (off + 255) & ~(size_t)255;
        void* p = ws + off;
        off += bytes;
        return p;
    };
    _Float16* h1h    = (_Float16*)alloc((size_t)N_NODES * F1 * 2);
    _Float16* hposth = (_Float16*)alloc((size_t)N_NODES * F1 * 2);
    _Float16* h2h    = (_Float16*)alloc((size_t)N_NODES * C2 * 2);
    float* als   = (float*)alloc((size_t)N_NODES * HEADS * 4);
    float* ald   = (float*)alloc((size_t)N_NODES * HEADS * 4);
    float* als2  = (float*)alloc((size_t)N_NODES * 4);
    float* ald2  = (float*)alloc((size_t)N_NODES * 4);
    int*   deg   = (int*)alloc((size_t)N_NODES * 4);
    int*   offs  = (int*)alloc((size_t)(N_NODES + 1) * 4);
    int*   cursor= (int*)alloc((size_t)N_NODES * 4);
    int*   bsum  = (int*)alloc((size_t)SCAN_B * 4);
    int*   boff  = (int*)alloc((size_t)SCAN_B * 4);
    int*   ssrc  = (int*)alloc((size_t)(N_EDGES + N_NODES) * 4);
    _Float16* Wp  = (_Float16*)alloc((size_t)256 * 256 * 2);
    _Float16* W2t = (_Float16*)alloc((size_t)16 * 256 * 2);
    (void)ws_size; (void)in_sizes; (void)n_in; (void)out_size;

    k_init_deg<<<(N_NODES + 255) / 256, 256, 0, stream>>>(deg);
    k_hist<<<(N_EDGES + 255) / 256, 256, 0, stream>>>(ei, deg);
    k_scan1<<<SCAN_B, 256, 0, stream>>>(deg, bsum);
    k_scan2<<<1, 256, 0, stream>>>(bsum, boff);
    k_scan3<<<SCAN_B, 256, 0, stream>>>(deg, boff, offs, cursor);
    k_scatter<<<(N_EDGES + N_NODES + 255) / 256, 256, 0, stream>>>(ei, cursor, ssrc);
    k_prep<<<257, 256, 0, stream>>>(W1, W2, Wp, W2t);
    k_gemm1<<<(N_NODES + 63) / 64, 256, 0, stream>>>(x, Wp, h1h);
    k_att1<<<N_NODES / 4, 256, 0, stream>>>(h1h, as1, ad1, als, ald);
    k_agg1<<<N_NODES, 64, 0, stream>>>(offs, ssrc, h1h, als, ald, b1, hposth);
    k_gemm2<<<(N_NODES + 63) / 64, 256, 0, stream>>>(hposth, W2t, as2, ad2, h2h, als2, ald2);
    k_agg2<<<N_NODES / 4, 256, 0, stream>>>(offs, ssrc, h2h, als2, ald2, b2, out);
}